// Round 3
// baseline (361.494 us; speedup 1.0000x reference)
//
#include <hip/hip_runtime.h>
#include <hip/hip_bf16.h>
#include <hip/hip_cooperative_groups.h>

namespace cg = cooperative_groups;

// Problem constants (B=8, S=1024, H=1024)
#define SB 8
#define SS 1024
#define SH 1024
#define LN_EPS 1e-5f

#define GK 1024
#define BM 128
#define BN 128
#define BK 32

typedef unsigned short u16;
typedef __attribute__((ext_vector_type(8))) short bf16x8;   // 8 bf16 in 4 VGPRs
typedef __attribute__((ext_vector_type(4))) float f32x4;

__device__ __forceinline__ u16 f2bf(float f) {
  __hip_bfloat16 h = __float2bfloat16(f);
  return *reinterpret_cast<u16*>(&h);
}
__device__ __forceinline__ float bf2f(u16 x) {
  unsigned v = ((unsigned)x) << 16;
  return __builtin_bit_cast(float, v);
}
__device__ __forceinline__ ushort4 pack4(float a, float b, float c, float d) {
  ushort4 o;
  o.x = f2bf(a); o.y = f2bf(b); o.z = f2bf(c); o.w = f2bf(d);
  return o;
}
__device__ __forceinline__ void gld16(const void* g, void* l) {
  __builtin_amdgcn_global_load_lds(
      (const __attribute__((address_space(1))) void*)g,
      (__attribute__((address_space(3))) void*)l, 16, 0, 0);
}

__device__ __forceinline__ void soft2(const float* __restrict__ du,
                                      const float* __restrict__ dd, int x,
                                      float& pu, float& pd) {
  const int sl = x & (SS - 1);
  if (sl == 0) { pu = 1.f; pd = 0.f; }
  else if (sl == SS - 1) { pu = 0.f; pd = 1.f; }
  else {
    const float a = du[x] * 0.03125f;  // 1/sqrt(1024)
    const float b = dd[x] * 0.03125f;
    const float m = fmaxf(a, b);
    const float eu = __expf(a - m), ed = __expf(b - m);
    const float inv = 1.f / (eu + ed);
    pu = eu * inv;
    pd = ed * inv;
  }
}

// ---------------------------------------------------------------------------
// Single cooperative kernel, 512 blocks x 256 threads.
// LDS = 53.3 KB (As 8K + Bs 8K + cn_s 36K + part 64B) -> 3 blk/CU by LDS;
// __launch_bounds__(256,2) pins >=2 blk/CU so the 512-block cooperative
// launch always validates (round-2 failure: zero-margin co-residency ->
// silent launch error -> all-zero outputs).
// Phase 1: blocks 0..255: PT 64x64 tile (PT[m,n]=Wk[m,:]·Wq[n,:]) + 8 LN rows.
//          blocks 256..271: wkbq (64 rows each) + 24 LN rows.
//          blocks 272..511: 24 LN rows.
// grid.sync()
// Phase 2: U-GEMM (cn @ PT^T) 128x128 tiles, m97-style single-buffered K-loop
//          (verified round 0/1); epilogue du/dd adjacent dots from LDS-staged
//          cn tile (XOR-swizzled both sides, verified round 1).
// grid.sync()
// Phase 3: softmax + elementwise + rowsum + outputs, 16 rows per block.
// ---------------------------------------------------------------------------
#define AS_OFF 0                 // 128x32 u16 = 8192 B
#define BS_OFF 8192              // 128x32 u16 = 8192 B
#define CN_OFF 16384             // 144x128 u16 = 36864 B
#define PR_OFF 53248             // 8 floats (p1[4], p2[4] / part[4])
#define SMEM_BYTES 53280

__global__ __launch_bounds__(256, 2) void mega(
    const float* __restrict__ x, const float* __restrict__ gamma,
    const float* __restrict__ beta, const float* __restrict__ Wq,
    const float* __restrict__ Wk, const float* __restrict__ bq,
    const float* __restrict__ prior, const int* __restrict__ mask,
    u16* __restrict__ cnb, u16* __restrict__ PT, float* __restrict__ wkbq,
    float* __restrict__ du, float* __restrict__ dd,
    float* __restrict__ g_out, float* __restrict__ ne_out) {
  __shared__ __align__(16) char smem[SMEM_BYTES];
  u16* As = (u16*)(smem + AS_OFF);
  u16* Bs = (u16*)(smem + BS_OFF);
  u16* cn_s = (u16*)(smem + CN_OFF);
  float* p1 = (float*)(smem + PR_OFF);
  float* p2 = p1 + 4;

  const int bid = blockIdx.x;  // 0..511
  const int tid = threadIdx.x;
  const int wave = tid >> 6, lane = tid & 63;
  cg::grid_group grid = cg::this_grid();

  // ======================= Phase 1 =======================
  if (bid < 256) {
    // ---- PT tile: C[m,n] = Wk[m,:]·Wq[n,:], 64x64, K=1024 ----
    const int m0 = (bid >> 4) * 64;
    const int n0 = (bid & 15) * 64;
    const int wn = wave * 16;
    const int l15 = lane & 15, q = lane >> 4;
    u16* tA = As;          // 4 KB
    u16* tB = As + 2048;   // 4 KB

    f32x4 acc[4] = {};
    const int srow = tid >> 2;
    const int scol = (tid & 3) * 8;
    const float* gA = Wk + (size_t)(m0 + srow) * SH + scol;
    const float* gB = Wq + (size_t)(n0 + srow) * SH + scol;
    u16* lA = &tA[srow * 32 + scol];
    u16* lB = &tB[srow * 32 + scol];

    for (int k0 = 0; k0 < SH; k0 += 32) {
      float4 a0 = *(const float4*)(gA + k0);
      float4 a1 = *(const float4*)(gA + k0 + 4);
      float4 b0 = *(const float4*)(gB + k0);
      float4 b1 = *(const float4*)(gB + k0 + 4);
      __syncthreads();
      *(ushort4*)lA = pack4(a0.x, a0.y, a0.z, a0.w);
      *(ushort4*)(lA + 4) = pack4(a1.x, a1.y, a1.z, a1.w);
      *(ushort4*)lB = pack4(b0.x, b0.y, b0.z, b0.w);
      *(ushort4*)(lB + 4) = pack4(b1.x, b1.y, b1.z, b1.w);
      __syncthreads();

      bf16x8 af[4];
#pragma unroll
      for (int fm = 0; fm < 4; ++fm)
        af[fm] = *(const bf16x8*)&tA[(fm * 16 + l15) * 32 + q * 8];
      bf16x8 bfr = *(const bf16x8*)&tB[(wn + l15) * 32 + q * 8];
#pragma unroll
      for (int fm = 0; fm < 4; ++fm)
        acc[fm] = __builtin_amdgcn_mfma_f32_16x16x32_bf16(af[fm], bfr, acc[fm],
                                                          0, 0, 0);
    }
    __syncthreads();
    // C/D layout: col=lane&15, row=(lane>>4)*4+reg  [m89-verified]
#pragma unroll
    for (int fm = 0; fm < 4; ++fm) {
      const int row0 = m0 + fm * 16 + q * 4;
      const int col = n0 + wn + l15;
#pragma unroll
      for (int r = 0; r < 4; ++r)
        PT[(size_t)(row0 + r) * SH + col] = f2bf(acc[fm][r]);
    }
  } else if (bid < 272) {
    // ---- wkbq[c] = Wk[c,:]·bq (only bias term surviving softmax shift) ----
    const int rbase = (bid - 256) * 64 + wave * 16;
    float4 bv[4];
#pragma unroll
    for (int j = 0; j < 4; ++j)
      bv[j] = *(const float4*)(bq + lane * 16 + 4 * j);
    for (int i = 0; i < 16; ++i) {
      const float* wr = Wk + (size_t)(rbase + i) * SH + lane * 16;
      float s = 0.f;
#pragma unroll
      for (int j = 0; j < 4; ++j) {
        float4 w4 = *(const float4*)(wr + 4 * j);
        s += w4.x * bv[j].x + w4.y * bv[j].y + w4.z * bv[j].z + w4.w * bv[j].w;
      }
#pragma unroll
      for (int off = 32; off > 0; off >>= 1) s += __shfl_down(s, off, 64);
      if (lane == 0) wkbq[rbase + i] = s;
    }
  }

  // ---- LayerNorm rows (all blocks; PT blocks take fewer rows) ----
  {
    int row0, nrows;
    if (bid < 256) { row0 = bid * 8; nrows = 8; }
    else { row0 = 2048 + (bid - 256) * 24; nrows = 24; }
    const float4 gm = *(const float4*)(gamma + 4 * tid);
    const float4 bt = *(const float4*)(beta + 4 * tid);
    for (int j = 0; j < nrows; ++j) {
      const int row = row0 + j;
      const float* xr = x + (size_t)row * SH;
      float4 v = *(const float4*)(xr + 4 * tid);

      float s = v.x + v.y + v.z + v.w;
#pragma unroll
      for (int off = 32; off > 0; off >>= 1) s += __shfl_down(s, off, 64);
      if (lane == 0) p1[wave] = s;
      __syncthreads();
      const float mu = (p1[0] + p1[1] + p1[2] + p1[3]) * (1.0f / SH);

      float d0 = v.x - mu, d1 = v.y - mu, d2 = v.z - mu, d3 = v.w - mu;
      float ss = d0 * d0 + d1 * d1 + d2 * d2 + d3 * d3;
#pragma unroll
      for (int off = 32; off > 0; off >>= 1) ss += __shfl_down(ss, off, 64);
      if (lane == 0) p2[wave] = ss;
      __syncthreads();
      const float rstd =
          rsqrtf((p2[0] + p2[1] + p2[2] + p2[3]) * (1.0f / SH) + LN_EPS);

      ushort4 o = pack4(d0 * rstd * gm.x + bt.x, d1 * rstd * gm.y + bt.y,
                        d2 * rstd * gm.z + bt.z, d3 * rstd * gm.w + bt.w);
      *(ushort4*)(cnb + (size_t)row * SH + 4 * tid) = o;
      if (tid == 0) {  // zero atomic accumulators (ws is poisoned)
        du[row] = 0.f;
        dd[row] = 0.f;
      }
    }
  }

  grid.sync();

  // ======================= Phase 2: U-GEMM =======================
  {
    const int bx = bid & 7, by = bid >> 3;
    const int m0 = by * BM, n0 = bx * BN;
    const int wm = (wave & 1) * 64, wn = (wave >> 1) * 64;
    const int l15 = lane & 15, q = lane >> 4;

    // cn_s staging DMAs: rows m0-1 .. m0+142 (clamped), cols [n0,n0+128).
    // Source col-block pre-swizzled (verified round 1): dest row rowi gets
    // global 16B-block  cb ^ (((rowi>>2)&3)<<1).  Drains at first barrier
    // of the K-loop; visible block-wide after every later barrier.
    {
      const int lr4 = lane >> 4;
      const int cb = lane & 15;
#pragma unroll
      for (int rd = 0; rd < 9; ++rd) {
        const int rowbase = rd * 16 + wave * 4;  // wave-uniform
        const int rowi = rowbase + lr4;
        const int sw = (rowi >> 2) & 3;
        int gr = m0 - 1 + rowi;
        gr = max(0, min(SB * SS - 1, gr));
        gld16(cnb + (size_t)gr * SH + n0 + ((cb ^ (sw << 1)) << 3),
              &cn_s[rowbase * 128]);
      }
    }

    f32x4 acc[4][4] = {};
    const int srow = tid >> 2;
    const int scol = 8 * (tid & 3);
    const u16* gA = cnb + (size_t)(m0 + srow) * GK + scol;
    const u16* gB = PT + (size_t)(n0 + srow) * GK + scol;
    u16* lA = &As[srow * BK + scol];
    u16* lB = &Bs[srow * BK + scol];

    for (int k0 = 0; k0 < GK; k0 += BK) {
      __syncthreads();
      gld16(gA + k0, lA);
      gld16(gA + (size_t)64 * GK + k0, lA + 64 * BK);
      gld16(gB + k0, lB);
      gld16(gB + (size_t)64 * GK + k0, lB + 64 * BK);
      __syncthreads();

      bf16x8 af[4], bfr[4];
#pragma unroll
      for (int fm = 0; fm < 4; ++fm)
        af[fm] = *(const bf16x8*)&As[(wm + fm * 16 + l15) * BK + q * 8];
#pragma unroll
      for (int fn = 0; fn < 4; ++fn)
        bfr[fn] = *(const bf16x8*)&Bs[(wn + fn * 16 + l15) * BK + q * 8];
#pragma unroll
      for (int fm = 0; fm < 4; ++fm)
#pragma unroll
        for (int fn = 0; fn < 4; ++fn)
          acc[fm][fn] = __builtin_amdgcn_mfma_f32_16x16x32_bf16(
              af[fm], bfr[fn], acc[fm][fn], 0, 0, 0);
    }

    // Epilogue: du[r] += sum_c (U[r,c]+wkbq[c]) * cn[r+1,c]; dd with r-1.
    float wb[4];
#pragma unroll
    for (int fn = 0; fn < 4; ++fn) wb[fn] = wkbq[n0 + wn + fn * 16 + l15];

#pragma unroll
    for (int fm = 0; fm < 4; ++fm) {
#pragma unroll
      for (int rr = 0; rr < 4; ++rr) {
        const int lr = wm + fm * 16 + q * 4 + rr;  // local row (r - m0)
        const int r = m0 + lr;
        const int sl = r & (SS - 1);
        const int ru = lr + 2;  // global row r+1 in cn_s
        const int swu = ((ru >> 2) & 3) << 4;
        const int swd = ((lr >> 2) & 3) << 4;
        const u16* up = &cn_s[ru * 128];
        const u16* dn = &cn_s[lr * 128];
        float sdu = 0.f, sdd = 0.f;
#pragma unroll
        for (int fn = 0; fn < 4; ++fn) {
          const int lc = wn + fn * 16 + l15;
          const float a = acc[fm][fn][rr] + wb[fn];
          sdu += a * bf2f(up[lc ^ swu]);
          sdd += a * bf2f(dn[lc ^ swd]);
        }
        if (sl == SS - 1) sdu = 0.f;  // no superdiagonal for last row of seq
        if (sl == 0) sdd = 0.f;       // no subdiagonal for first row
#pragma unroll
        for (int m = 1; m < 16; m <<= 1) {
          sdu += __shfl_xor(sdu, m, 64);
          sdd += __shfl_xor(sdd, m, 64);
        }
        if (l15 == 0) {
          atomicAdd(&du[r], sdu);
          atomicAdd(&dd[r], sdd);
        }
      }
    }
  }

  grid.sync();

  // ======================= Phase 3: outputs =======================
  {
    float* part = p1;
    const float nbz = 3.1622776601683795e-5f;  // sqrt(1e-9)
    for (int j = 0; j < 16; ++j) {
      const int r = bid * 16 + j;
      const int b = r >> 10, i = r & (SS - 1);

      float nb_im1 = nbz, nb_ip1 = nbz;
      if (i >= 1) {
        float pu_m, pd_m, pu_c, pd_c;
        soft2(du, dd, r - 1, pu_m, pd_m);
        soft2(du, dd, r, pu_c, pd_c);
        nb_im1 = sqrtf(pu_m * pd_c + 1e-9f);
      }
      if (i <= SS - 2) {
        float pu_c, pd_c, pu_p, pd_p;
        soft2(du, dd, r, pu_c, pd_c);
        soft2(du, dd, r + 1, pu_p, pd_p);
        nb_ip1 = sqrtf(pu_c * pd_p + 1e-9f);
      }

      const float* prow = prior + (size_t)r * SS;
      float4 pv = *(const float4*)(prow + 4 * tid);
      const int* mrow = mask + b * SS;
      const float padi = (mrow[i] != 0) ? 1.f : 0.f;
      int4 mk = *(const int4*)(mrow + 4 * tid);

      float ne[4], gsum = 0.f;
#pragma unroll
      for (int v = 0; v < 4; ++v) {
        const int k = 4 * tid + v;
        const float p = (&pv.x)[v];
        const float nb = (k == i - 1) ? nb_im1 : (k == i + 1) ? nb_ip1 : nbz;
        const float n = p + (1.f - p) * nb;
        ne[v] = n;
        gsum += (k == i) ? (2.f + 1e-9f) : (1.f + n);
      }

#pragma unroll
      for (int off = 32; off > 0; off >>= 1) gsum += __shfl_down(gsum, off, 64);
      if (lane == 0) part[wave] = gsum;
      __syncthreads();
      const float inv = 1.f / (part[0] + part[1] + part[2] + part[3] + 1e-9f);
      __syncthreads();  // protect part[] before next row's write

      float4 go, no;
#pragma unroll
      for (int v = 0; v < 4; ++v) {
        const int k = 4 * tid + v;
        const float padk = ((&mk.x)[v] != 0) ? 1.f : 0.f;
        const float f2 = padi * padk;
        const float gt = (k == i) ? (2.f + 1e-9f) : (1.f + ne[v]);
        (&go.x)[v] = gt * inv * f2;
        (&no.x)[v] = ne[v] * f2;
      }
      *(float4*)(g_out + (size_t)r * SS + 4 * tid) = go;
      *(float4*)(ne_out + (size_t)r * SS + 4 * tid) = no;
    }
  }
}

// ---------------------------------------------------------------------------
extern "C" void kernel_launch(void* const* d_in, const int* in_sizes, int n_in,
                              void* d_out, int out_size, void* d_ws, size_t ws_size,
                              hipStream_t stream) {
  const float* context = (const float*)d_in[0];
  const int* mask = (const int*)d_in[1];
  const float* prior = (const float*)d_in[2];
  const float* gamma = (const float*)d_in[3];
  const float* beta = (const float*)d_in[4];
  const float* Wk = (const float*)d_in[5];
  const float* bk = (const float*)d_in[6];  // cancels in softmax shift
  const float* Wq = (const float*)d_in[7];
  const float* bq = (const float*)d_in[8];
  (void)bk;

  float* out_g = (float*)d_out;
  float* out_n = out_g + (size_t)SB * SS * SS;

  char* ws = (char*)d_ws;
  u16* cnb = (u16*)ws;                                   // 16 MB bf16 [8192,1024]
  u16* PT = (u16*)(ws + ((size_t)16 << 20));             // 2 MB bf16 [1024,1024]
  float* wkbq = (float*)(ws + ((size_t)18 << 20));       // 4 KB
  float* du = (float*)(ws + ((size_t)19 << 20));         // 32 KB
  float* dd = (float*)(ws + ((size_t)20 << 20));         // 32 KB

  void* kargs[] = {(void*)&context, (void*)&gamma, (void*)&beta, (void*)&Wq,
                   (void*)&Wk,      (void*)&bq,    (void*)&prior, (void*)&mask,
                   (void*)&cnb,     (void*)&PT,    (void*)&wkbq,  (void*)&du,
                   (void*)&dd,      (void*)&out_g, (void*)&out_n};
  hipLaunchCooperativeKernel((void*)mega, dim3(512), dim3(256), kargs, 0,
                             stream);
}

// Round 4
// 188.827 us; speedup vs baseline: 1.9144x; 1.9144x over previous
//
#include <hip/hip_runtime.h>
#include <hip/hip_bf16.h>

// Problem constants (B=8, S=1024, H=1024)
#define SB 8
#define SS 1024
#define SH 1024
#define LN_EPS 1e-5f

typedef unsigned short u16;
typedef __attribute__((ext_vector_type(8))) short bf16x8;   // 8 bf16 in 4 VGPRs
typedef __attribute__((ext_vector_type(4))) float f32x4;

__device__ __forceinline__ u16 f2bf(float f) {
  __hip_bfloat16 h = __float2bfloat16(f);
  return *reinterpret_cast<u16*>(&h);
}
__device__ __forceinline__ float bf2f(u16 x) {
  unsigned v = ((unsigned)x) << 16;
  return __builtin_bit_cast(float, v);
}
__device__ __forceinline__ ushort4 pack4(float a, float b, float c, float d) {
  ushort4 o;
  o.x = f2bf(a); o.y = f2bf(b); o.z = f2bf(c); o.w = f2bf(d);
  return o;
}
__device__ __forceinline__ void gld16(const void* g, void* l) {
  __builtin_amdgcn_global_load_lds(
      (const __attribute__((address_space(1))) void*)g,
      (__attribute__((address_space(3))) void*)l, 16, 0, 0);
}

// ---------------------------------------------------------------------------
// Kernel 1: PREP + PT-GEMM + wkbq, fused (verified round 1).
//   Blocks 0..255   : PT 64x64 tiles (PT[m,n] = Wk[m,:]·Wq[n,:]).
//   Blocks 256..271 : wkbq[c] = Wk[c,:]·bq.
//   Blocks 272..8463: LayerNorm row -> bf16 cnb; zero du/dd.
// ---------------------------------------------------------------------------
#define NPT 256
#define NWB 16
#define LNB0 (NPT + NWB)

__global__ __launch_bounds__(256) void prep_pt(
    const float* __restrict__ x, const float* __restrict__ gamma,
    const float* __restrict__ beta, const float* __restrict__ Wq,
    const float* __restrict__ Wk, const float* __restrict__ bq,
    u16* __restrict__ cnb, u16* __restrict__ PT, float* __restrict__ wkbq,
    float* __restrict__ du, float* __restrict__ dd) {
  __shared__ float p1[4], p2[4];
  __shared__ u16 As[64 * 32];
  __shared__ u16 Bs[64 * 32];
  const int blk = blockIdx.x;
  const int t = threadIdx.x;
  const int wave = t >> 6, lane = t & 63;

  if (blk >= LNB0) {
    // ---- LayerNorm row ----
    const int row = blk - LNB0;
    const float* xr = x + (size_t)row * SH;
    float4 v = *(const float4*)(xr + 4 * t);

    float s = v.x + v.y + v.z + v.w;
#pragma unroll
    for (int off = 32; off > 0; off >>= 1) s += __shfl_down(s, off, 64);
    if (lane == 0) p1[wave] = s;
    __syncthreads();
    const float mu = (p1[0] + p1[1] + p1[2] + p1[3]) * (1.0f / SH);

    float d0 = v.x - mu, d1 = v.y - mu, d2 = v.z - mu, d3 = v.w - mu;
    float ss = d0 * d0 + d1 * d1 + d2 * d2 + d3 * d3;
#pragma unroll
    for (int off = 32; off > 0; off >>= 1) ss += __shfl_down(ss, off, 64);
    if (lane == 0) p2[wave] = ss;
    __syncthreads();
    const float rstd =
        rsqrtf((p2[0] + p2[1] + p2[2] + p2[3]) * (1.0f / SH) + LN_EPS);

    float4 gm = *(const float4*)(gamma + 4 * t);
    float4 bt = *(const float4*)(beta + 4 * t);
    ushort4 o = pack4(d0 * rstd * gm.x + bt.x, d1 * rstd * gm.y + bt.y,
                      d2 * rstd * gm.z + bt.z, d3 * rstd * gm.w + bt.w);
    *(ushort4*)(cnb + (size_t)row * SH + 4 * t) = o;
    if (t == 0) {  // zero atomic accumulators (ws is 0xAA-poisoned)
      du[row] = 0.f;
      dd[row] = 0.f;
    }
  } else if (blk < NPT) {
    // ---- PT tile: C[m,n] = Wk[m,:]·Wq[n,:], 64x64, K=1024 ----
    const int m0 = (blk >> 4) * 64;
    const int n0 = (blk & 15) * 64;
    const int wn = wave * 16;
    const int l15 = lane & 15, q = lane >> 4;

    f32x4 acc[4] = {};
    const int srow = t >> 2;
    const int scol = (t & 3) * 8;
    const float* gA = Wk + (size_t)(m0 + srow) * SH + scol;
    const float* gB = Wq + (size_t)(n0 + srow) * SH + scol;
    u16* lA = &As[srow * 32 + scol];
    u16* lB = &Bs[srow * 32 + scol];

    for (int k0 = 0; k0 < SH; k0 += 32) {
      float4 a0 = *(const float4*)(gA + k0);
      float4 a1 = *(const float4*)(gA + k0 + 4);
      float4 b0 = *(const float4*)(gB + k0);
      float4 b1 = *(const float4*)(gB + k0 + 4);
      __syncthreads();
      *(ushort4*)lA = pack4(a0.x, a0.y, a0.z, a0.w);
      *(ushort4*)(lA + 4) = pack4(a1.x, a1.y, a1.z, a1.w);
      *(ushort4*)lB = pack4(b0.x, b0.y, b0.z, b0.w);
      *(ushort4*)(lB + 4) = pack4(b1.x, b1.y, b1.z, b1.w);
      __syncthreads();

      bf16x8 af[4];
#pragma unroll
      for (int fm = 0; fm < 4; ++fm)
        af[fm] = *(const bf16x8*)&As[(fm * 16 + l15) * 32 + q * 8];
      bf16x8 bfr = *(const bf16x8*)&Bs[(wn + l15) * 32 + q * 8];
#pragma unroll
      for (int fm = 0; fm < 4; ++fm)
        acc[fm] = __builtin_amdgcn_mfma_f32_16x16x32_bf16(af[fm], bfr, acc[fm],
                                                          0, 0, 0);
    }

    // C/D layout: col=lane&15, row=(lane>>4)*4+reg  [m89-verified]
#pragma unroll
    for (int fm = 0; fm < 4; ++fm) {
      const int row0 = m0 + fm * 16 + q * 4;
      const int col = n0 + wn + l15;
#pragma unroll
      for (int r = 0; r < 4; ++r)
        PT[(size_t)(row0 + r) * SH + col] = f2bf(acc[fm][r]);
    }
  } else {
    // ---- wkbq: 16 blocks x 64 rows; one row per wave-iteration ----
    const int rbase = (blk - NPT) * 64 + wave * 16;
    float4 bv[4];
#pragma unroll
    for (int j = 0; j < 4; ++j)
      bv[j] = *(const float4*)(bq + lane * 16 + 4 * j);
    for (int i = 0; i < 16; ++i) {
      const float* wr = Wk + (size_t)(rbase + i) * SH + lane * 16;
      float s = 0.f;
#pragma unroll
      for (int j = 0; j < 4; ++j) {
        float4 w4 = *(const float4*)(wr + 4 * j);
        s += w4.x * bv[j].x + w4.y * bv[j].y + w4.z * bv[j].z + w4.w * bv[j].w;
      }
#pragma unroll
      for (int off = 32; off > 0; off >>= 1) s += __shfl_down(s, off, 64);
      if (lane == 0) wkbq[rbase + i] = s;
    }
  }
}

// ---------------------------------------------------------------------------
// Kernel 2: fused U-GEMM + bias + adjacent dots.
// NEW (T4, m218/AITER pattern): double-buffered LDS, stage tile t+1 before
// computing tile t, counted `s_waitcnt vmcnt(4)` + RAW s_barrier — next
// tile's 4 DMAs stay in flight across the barrier (never drain to 0 in the
// main loop). Second raw barrier (no drain) protects buf[cur] before the
// next iteration's stage overwrites it (safe: every wave's ds_reads are
// consumed by its MFMAs before it reaches the barrier).
// vmcnt ledger (per wave): prologue = 9 cn_s DMAs + 4 tile-0 = 13 out.
//   iter t: +4 (tile t+1) -> wait vmcnt(4) leaves exactly tile t+1 in
//   flight; cn_s fully drained at iter 0. Last tile peeled with vmcnt(0).
// cn_s XOR swizzle (both sides) verified round 1.
// LDS: 2*8K(A) + 2*8K(B) + 36K(cn_s) = 68.9 KB -> 2 blk/CU.
// ---------------------------------------------------------------------------
#define GK 1024
#define BM 128
#define BN 128
#define BK 32

__global__ __launch_bounds__(256) void ugemm_fused(const u16* __restrict__ A,
                                                   const u16* __restrict__ Bt,
                                                   const u16* __restrict__ cnb,
                                                   const float* __restrict__ wkbq,
                                                   float* __restrict__ du,
                                                   float* __restrict__ dd) {
  __shared__ u16 As[2][BM * BK];
  __shared__ u16 Bs[2][BN * BK];
  __shared__ u16 cn_s[144 * 128];
  const int tid = threadIdx.x;
  // T1 XCD swizzle (bijective, 512 % 8 == 0): XCD x gets logical tiles
  // [x*64, (x+1)*64) = 8 consecutive A-panels -> within-L2 A reuse.
  const int swz = (blockIdx.x & 7) * 64 + (blockIdx.x >> 3);
  const int m0 = (swz >> 3) * BM;
  const int n0 = (swz & 7) * BN;
  const int wave = tid >> 6, lane = tid & 63;
  const int wm = (wave & 1) * 64, wn = (wave >> 1) * 64;
  const int l15 = lane & 15, q = lane >> 4;

  // ---- cn_s staging DMAs: rows m0-1 .. m0+142 (clamped), cols [n0,n0+128).
  //      Source col-block pre-swizzled: dest row rowi gets global 16B-block
  //      cb ^ (((rowi>>2)&3)<<1).   (verified round 1)
  {
    const int lr4 = lane >> 4;
    const int cb = lane & 15;
#pragma unroll
    for (int rd = 0; rd < 9; ++rd) {
      const int rowbase = rd * 16 + wave * 4;  // wave-uniform
      const int rowi = rowbase + lr4;
      const int sw = (rowi >> 2) & 3;
      int gr = m0 - 1 + rowi;
      gr = max(0, min(SB * SS - 1, gr));
      gld16(cnb + (size_t)gr * SH + n0 + ((cb ^ (sw << 1)) << 3),
            &cn_s[rowbase * 128]);
    }
  }

  f32x4 acc[4][4] = {};
  const int srow = tid >> 2;
  const int scol = 8 * (tid & 3);
  const u16* gA = A + (size_t)(m0 + srow) * GK + scol;
  const u16* gB = Bt + (size_t)(n0 + srow) * GK + scol;
  const int so = srow * BK + scol;

  // Prologue: tile 0 -> buf 0.
  gld16(gA, &As[0][so]);
  gld16(gA + (size_t)64 * GK, &As[0][64 * BK + so]);
  gld16(gB, &Bs[0][so]);
  gld16(gB + (size_t)64 * GK, &Bs[0][64 * BK + so]);

  int cur = 0;
  for (int t = 0; t < 31; ++t) {
    const int k1 = (t + 1) * BK;
    // stage tile t+1 into buf[cur^1] (its readers finished at the previous
    // iteration's trailing barrier)
    u16* nA = &As[cur ^ 1][so];
    u16* nB = &Bs[cur ^ 1][so];
    gld16(gA + k1, nA);
    gld16(gA + (size_t)64 * GK + k1, nA + 64 * BK);
    gld16(gB + k1, nB);
    gld16(gB + (size_t)64 * GK + k1, nB + 64 * BK);

    // tile t complete (tile t+1's 4 DMAs stay in flight across the barrier)
    asm volatile("s_waitcnt vmcnt(4)" ::: "memory");
    __builtin_amdgcn_sched_barrier(0);
    __builtin_amdgcn_s_barrier();
    __builtin_amdgcn_sched_barrier(0);

    const u16* cA = As[cur];
    const u16* cB = Bs[cur];
    bf16x8 af[4], bfr[4];
#pragma unroll
    for (int fm = 0; fm < 4; ++fm)
      af[fm] = *(const bf16x8*)&cA[(wm + fm * 16 + l15) * BK + q * 8];
#pragma unroll
    for (int fn = 0; fn < 4; ++fn)
      bfr[fn] = *(const bf16x8*)&cB[(wn + fn * 16 + l15) * BK + q * 8];
#pragma unroll
    for (int fm = 0; fm < 4; ++fm)
#pragma unroll
      for (int fn = 0; fn < 4; ++fn)
        acc[fm][fn] = __builtin_amdgcn_mfma_f32_16x16x32_bf16(
            af[fm], bfr[fn], acc[fm][fn], 0, 0, 0);

    // raw barrier, NO drain: all waves' reads of buf[cur] are already
    // consumed; next iteration may overwrite it.
    __builtin_amdgcn_s_barrier();
    __builtin_amdgcn_sched_barrier(0);
    cur ^= 1;
  }

  // Final tile (peeled): nothing left in flight afterwards.
  asm volatile("s_waitcnt vmcnt(0)" ::: "memory");
  __builtin_amdgcn_sched_barrier(0);
  __builtin_amdgcn_s_barrier();
  __builtin_amdgcn_sched_barrier(0);
  {
    const u16* cA = As[cur];
    const u16* cB = Bs[cur];
    bf16x8 af[4], bfr[4];
#pragma unroll
    for (int fm = 0; fm < 4; ++fm)
      af[fm] = *(const bf16x8*)&cA[(wm + fm * 16 + l15) * BK + q * 8];
#pragma unroll
    for (int fn = 0; fn < 4; ++fn)
      bfr[fn] = *(const bf16x8*)&cB[(wn + fn * 16 + l15) * BK + q * 8];
#pragma unroll
    for (int fm = 0; fm < 4; ++fm)
#pragma unroll
      for (int fn = 0; fn < 4; ++fn)
        acc[fm][fn] = __builtin_amdgcn_mfma_f32_16x16x32_bf16(
            af[fm], bfr[fn], acc[fm][fn], 0, 0, 0);
  }

  // Epilogue: du[r] += sum_c (U[r,c]+wkbq[c]) * cn[r+1,c]; dd with r-1.
  // cn_s complete+visible since iter 0's waitcnt+barrier.
  float wb[4];
#pragma unroll
  for (int fn = 0; fn < 4; ++fn) wb[fn] = wkbq[n0 + wn + fn * 16 + l15];

#pragma unroll
  for (int fm = 0; fm < 4; ++fm) {
#pragma unroll
    for (int rr = 0; rr < 4; ++rr) {
      const int lr = wm + fm * 16 + q * 4 + rr;  // local row (r - m0)
      const int r = m0 + lr;
      const int sl = r & (SS - 1);
      const int ru = lr + 2;  // global row r+1 in cn_s
      const int swu = ((ru >> 2) & 3) << 4;
      const int swd = ((lr >> 2) & 3) << 4;
      const u16* up = &cn_s[ru * 128];
      const u16* dn = &cn_s[lr * 128];
      float sdu = 0.f, sdd = 0.f;
#pragma unroll
      for (int fn = 0; fn < 4; ++fn) {
        const int lc = wn + fn * 16 + l15;
        const float a = acc[fm][fn][rr] + wb[fn];
        sdu += a * bf2f(up[lc ^ swu]);
        sdd += a * bf2f(dn[lc ^ swd]);
      }
      if (sl == SS - 1) sdu = 0.f;  // no superdiagonal for last row of seq
      if (sl == 0) sdd = 0.f;       // no subdiagonal for first row
#pragma unroll
      for (int m = 1; m < 16; m <<= 1) {
        sdu += __shfl_xor(sdu, m, 64);
        sdd += __shfl_xor(sdd, m, 64);
      }
      if (l15 == 0) {
        atomicAdd(&du[r], sdu);
        atomicAdd(&dd[r], sdd);
      }
    }
  }
}

// ---------------------------------------------------------------------------
// Kernel 3: fused softmax + elementwise + rowsum + outputs (verified).
// ---------------------------------------------------------------------------
__device__ __forceinline__ void soft2(const float* __restrict__ du,
                                      const float* __restrict__ dd, int x,
                                      float& pu, float& pd) {
  const int sl = x & (SS - 1);
  if (sl == 0) { pu = 1.f; pd = 0.f; }
  else if (sl == SS - 1) { pu = 0.f; pd = 1.f; }
  else {
    const float a = du[x] * 0.03125f;  // 1/sqrt(1024)
    const float b = dd[x] * 0.03125f;
    const float m = fmaxf(a, b);
    const float eu = __expf(a - m), ed = __expf(b - m);
    const float inv = 1.f / (eu + ed);
    pu = eu * inv;
    pd = ed * inv;
  }
}

__global__ __launch_bounds__(256) void rows_fused(const float* __restrict__ prior,
                                                  const int* __restrict__ mask,
                                                  const float* __restrict__ du,
                                                  const float* __restrict__ dd,
                                                  float* __restrict__ g_out,
                                                  float* __restrict__ ne_out) {
  const int r = blockIdx.x;
  const int b = r >> 10, i = r & (SS - 1);
  const int t = threadIdx.x;
  const int wave = t >> 6, lane = t & 63;
  const float nbz = 3.1622776601683795e-5f;  // sqrt(1e-9)

  float nb_im1 = nbz, nb_ip1 = nbz;
  if (i >= 1) {
    float pu_m, pd_m, pu_c, pd_c;
    soft2(du, dd, r - 1, pu_m, pd_m);
    soft2(du, dd, r, pu_c, pd_c);
    nb_im1 = sqrtf(pu_m * pd_c + 1e-9f);
  }
  if (i <= SS - 2) {
    float pu_c, pd_c, pu_p, pd_p;
    soft2(du, dd, r, pu_c, pd_c);
    soft2(du, dd, r + 1, pu_p, pd_p);
    nb_ip1 = sqrtf(pu_c * pd_p + 1e-9f);
  }

  const float* prow = prior + (size_t)r * SS;
  float4 pr = *(const float4*)(prow + 4 * t);
  const int* mrow = mask + b * SS;
  const float padi = (mrow[i] != 0) ? 1.f : 0.f;
  int4 mk = *(const int4*)(mrow + 4 * t);

  float ne[4], gsum = 0.f;
#pragma unroll
  for (int v = 0; v < 4; ++v) {
    const int k = 4 * t + v;
    const float p = (&pr.x)[v];
    const float nb = (k == i - 1) ? nb_im1 : (k == i + 1) ? nb_ip1 : nbz;
    const float n = p + (1.f - p) * nb;
    ne[v] = n;
    gsum += (k == i) ? (2.f + 1e-9f) : (1.f + n);
  }

  __shared__ float part[4];
#pragma unroll
  for (int off = 32; off > 0; off >>= 1) gsum += __shfl_down(gsum, off, 64);
  if (lane == 0) part[wave] = gsum;
  __syncthreads();
  const float inv = 1.f / (part[0] + part[1] + part[2] + part[3] + 1e-9f);

  float4 go, no;
#pragma unroll
  for (int v = 0; v < 4; ++v) {
    const int k = 4 * t + v;
    const float padk = ((&mk.x)[v] != 0) ? 1.f : 0.f;
    const float f2 = padi * padk;
    const float gt = (k == i) ? (2.f + 1e-9f) : (1.f + ne[v]);
    (&go.x)[v] = gt * inv * f2;
    (&no.x)[v] = ne[v] * f2;
  }
  *(float4*)(g_out + (size_t)r * SS + 4 * t) = go;
  *(float4*)(ne_out + (size_t)r * SS + 4 * t) = no;
}

// ---------------------------------------------------------------------------
extern "C" void kernel_launch(void* const* d_in, const int* in_sizes, int n_in,
                              void* d_out, int out_size, void* d_ws, size_t ws_size,
                              hipStream_t stream) {
  const float* context = (const float*)d_in[0];
  const int* mask = (const int*)d_in[1];
  const float* prior = (const float*)d_in[2];
  const float* gamma = (const float*)d_in[3];
  const float* beta = (const float*)d_in[4];
  const float* Wk = (const float*)d_in[5];
  const float* bk = (const float*)d_in[6];  // cancels in softmax shift
  const float* Wq = (const float*)d_in[7];
  const float* bq = (const float*)d_in[8];
  (void)bk;

  float* out_g = (float*)d_out;
  float* out_n = out_g + (size_t)SB * SS * SS;

  char* ws = (char*)d_ws;
  u16* cnb = (u16*)ws;                                   // 16 MB bf16 [8192,1024]
  u16* PT = (u16*)(ws + ((size_t)16 << 20));             // 2 MB bf16 [1024,1024]
  float* wkbq = (float*)(ws + ((size_t)18 << 20));       // 4 KB
  float* du = (float*)(ws + ((size_t)19 << 20));         // 32 KB
  float* dd = (float*)(ws + ((size_t)20 << 20));         // 32 KB

  // LN + PT-GEMM + wkbq fused; PT blocks first so they overlap the LN stream.
  prep_pt<<<LNB0 + SB * SS, 256, 0, stream>>>(context, gamma, beta, Wq, Wk, bq,
                                              cnb, PT, wkbq, du, dd);
  // U never materialized; du/dd accumulated in LDS-staged epilogue.
  ugemm_fused<<<512, 256, 0, stream>>>(cnb, PT, cnb, wkbq, du, dd);
  rows_fused<<<SB * SS, 256, 0, stream>>>(prior, mask, du, dd, out_g, out_n);
}